// Round 3
// baseline (11582.635 us; speedup 1.0000x reference)
//
#include <hip/hip_runtime.h>
#include <math.h>

// ---------------------------------------------------------------------------
// 2-layer LSTM, B=64 T=512 I=256 H=768, fp32 in/out.
// Round 3: ONE persistent kernel (192 WGs, all co-resident). Weights live in
// VGPRs for the entire 512-step run; c-state in registers. Layer 0 (WGs 0-95)
// and layer 1 (WGs 96-191) pipeline through depth-4 fp16 h-rings synchronized
// by per-step flags (agent-scope atomics + acquire/release fences, which on
// gfx950 emit the L2 inv/wb needed for cross-XCD visibility).
// fp16 MFMA 16x16x32, fragment-major packed operands (round-2 layout).
// ---------------------------------------------------------------------------

#define B_   64
#define T_   512
#define I_   256
#define H_   768
#define G4H  3072

constexpr size_t BTH = (size_t)B_ * T_ * H_;   // 25165824
constexpr size_t BH  = (size_t)B_ * H_;        // 49152

using f16_t = _Float16;
using f16x8 = __attribute__((ext_vector_type(8))) _Float16;
using f32x4 = __attribute__((ext_vector_type(4))) float;

#define MFMA(a, b, c) __builtin_amdgcn_mfma_f32_16x16x32_f16((a), (b), (c), 0, 0, 0)

// ---------------------------------------------------------------------------
// Prep kernels (round-2 layouts, unchanged).
__global__ void k_packW(const float* __restrict__ src, f16_t* __restrict__ dst,
                        int K, int KC, int total) {
  int i = blockIdx.x * blockDim.x + threadIdx.x;
  int stride = gridDim.x * blockDim.x;
  for (; i < total; i += stride) {
    int e = i & 7;
    int lane = (i >> 3) & 63;
    int rest = i >> 9;          // ptile*KC + kc
    int kc = rest % KC;
    int ptile = rest / KC;
    int p = ptile * 16 + (lane & 15);
    int k = kc * 32 + (lane >> 4) * 8 + e;
    int r = (p & 3) * H_ + (p >> 2);
    dst[i] = (f16_t)src[(size_t)r * K + k];
  }
}

__global__ void k_packX(const float* __restrict__ x, f16_t* __restrict__ dst) {
  int i = blockIdx.x * blockDim.x + threadIdx.x;
  int stride = gridDim.x * blockDim.x;
  const int total = 4 * T_ * 8 * 64 * 8;  // 8,388,608
  for (; i < total; i += stride) {
    int e = i & 7;
    int lane = (i >> 3) & 63;
    int kc = (i >> 9) & 7;
    int t = (i >> 12) & 511;
    int mtile = i >> 21;
    int b = mtile * 16 + (lane & 15);
    int k = kc * 32 + (lane >> 4) * 8 + e;
    dst[i] = (f16_t)x[((size_t)b * T_ + t) * I_ + k];
  }
}

__global__ void k_bias(const float* __restrict__ bih, const float* __restrict__ bhh,
                       float* __restrict__ bsum) {
  int p = blockIdx.x * blockDim.x + threadIdx.x;
  if (p < G4H) {
    int r = (p & 3) * H_ + (p >> 2);
    bsum[p] = bih[r] + bhh[r];
  }
}

__global__ void k_zero(int4* __restrict__ d, int n) {
  int i = blockIdx.x * blockDim.x + threadIdx.x;
  if (i < n) d[i] = make_int4(0, 0, 0, 0);
}

__device__ __forceinline__ float sigf(float v) { return 1.0f / (1.0f + expf(-v)); }

__device__ __forceinline__ void wait_ge(const int* p, int target) {
  while (__hip_atomic_load(p, __ATOMIC_RELAXED, __HIP_MEMORY_SCOPE_AGENT) < target)
    __builtin_amdgcn_s_sleep(2);
}

template <int KCW>
__device__ __forceinline__ void loadW(const f16_t* __restrict__ Wf, int pt0, int KC,
                                      int kc0, int laneo, f16x8 (&W)[2][KCW]) {
#pragma unroll
  for (int p = 0; p < 2; ++p)
#pragma unroll
    for (int i = 0; i < KCW; ++i)
      W[p][i] = *(const f16x8*)(Wf + ((size_t)(pt0 + p) * KC + kc0 + i) * 512 + laneo);
}

template <int KCW>
__device__ __forceinline__ void gemm_frag(const f16_t* __restrict__ A0,
                                          const f16_t* __restrict__ A1,
                                          const f16x8 (&W)[2][KCW], f32x4& a00,
                                          f32x4& a01, f32x4& a10, f32x4& a11) {
#pragma unroll
  for (int i = 0; i < KCW; ++i) {
    f16x8 x0 = *(const f16x8*)(A0 + (size_t)i * 512);
    f16x8 x1 = *(const f16x8*)(A1 + (size_t)i * 512);
    a00 = MFMA(x0, W[0][i], a00);
    a01 = MFMA(x0, W[1][i], a01);
    a10 = MFMA(x1, W[0][i], a10);
    a11 = MFMA(x1, W[1][i], a11);
  }
}

// ---------------------------------------------------------------------------
// Per-layer persistent loop. 8 waves = mg(2: mtile pairs) x kg(4: K-quarters).
// Each wave: 2x2 register tile (2 mtiles x 2 ptiles), W-frags in VGPRs.
// L0: kg0 = x (kc 0..7 of Xf), kg1-3 = h0 (8 kc each of 24).
// L1: kg0-1 = h0 (12 kc each), kg2-3 = h1 (12 kc each).
// Rings: [slot(4)][mtile(4)][kc(24)][512] fp16; slot stride 49152 = BH.
template <int KCW, bool IS_L1>
__device__ __forceinline__ void run_layer(
    int ws, const f16_t* __restrict__ Xf, const f16_t* __restrict__ Wihf,
    const f16_t* __restrict__ Whhf, const float* __restrict__ bsum,
    f16_t* __restrict__ h0f, f16_t* __restrict__ h1f, int* __restrict__ cnt0,
    int* __restrict__ cnt1, float* __restrict__ out, float (*pre)[64][33],
    float* bsL) {
  const int tid = threadIdx.x;
  const int wave = tid >> 6, lane = tid & 63;
  const int kg = wave & 3, mg = wave >> 2;
  const int laneo = lane * 8;
  const int pt0 = ws * 2;
  const int m0 = mg * 2;
  const int l15 = lane & 15, l4 = lane >> 4;

  if (tid < 32) bsL[tid] = bsum[ws * 32 + tid];

  f16x8 W[2][KCW];
  if constexpr (!IS_L1) {
    if (kg == 0) loadW<KCW>(Wihf, pt0, 8, 0, laneo, W);
    else         loadW<KCW>(Whhf, pt0, 24, (kg - 1) * 8, laneo, W);
  } else {
    if (kg < 2)  loadW<KCW>(Wihf, pt0, 24, kg * 12, laneo, W);
    else         loadW<KCW>(Whhf, pt0, 24, (kg - 2) * 12, laneo, W);
  }

  float c_reg = 0.f;
  const int u = tid & 7, b = tid >> 3;
  const int j = ws * 8 + u;
  const size_t hbase = ((size_t)(b >> 4) * 24 + (j >> 5)) * 512 +
                       (size_t)(((j >> 3) & 3) * 16 + (b & 15)) * 8 + (j & 7);
  f16_t* ring = IS_L1 ? h1f : h0f;

  __syncthreads();

  for (int t = 0; t < T_; ++t) {
    // ---- wait for inputs / ring safety ----
    if constexpr (!IS_L1) {
      if (kg != 0) {
        if (lane == 0) {
          if (t >= 1) wait_ge(cnt0 + t - 1, 96);   // h0[t-1] ready
          if (t >= 4) wait_ge(cnt1 + t - 4, 96);   // h0[t-4] slot reusable
        }
        __builtin_amdgcn_fence(__ATOMIC_ACQUIRE, "agent");
      }
    } else {
      if (lane == 0) {
        if (kg < 2) wait_ge(cnt0 + t, 96);               // h0[t] ready
        else if (t >= 1) wait_ge(cnt1 + t - 1, 96);      // h1[t-1] ready
      }
      __builtin_amdgcn_fence(__ATOMIC_ACQUIRE, "agent");
    }

    f32x4 a00 = {0.f, 0.f, 0.f, 0.f};
    f32x4 a01 = {0.f, 0.f, 0.f, 0.f};
    f32x4 a10 = {0.f, 0.f, 0.f, 0.f};
    f32x4 a11 = {0.f, 0.f, 0.f, 0.f};

    if constexpr (!IS_L1) {
      if (kg == 0) {
        const f16_t* A0 = Xf + (((size_t)m0 * T_ + t) * 8) * 512 + laneo;
        gemm_frag<KCW>(A0, A0 + (size_t)T_ * 4096, W, a00, a01, a10, a11);
      } else {
        const f16_t* A0 = h0f +
            (((size_t)((t + 3) & 3) * 4 + m0) * 24 + (kg - 1) * 8) * 512 + laneo;
        gemm_frag<KCW>(A0, A0 + 12288, W, a00, a01, a10, a11);
      }
    } else {
      if (kg < 2) {
        const f16_t* A0 = h0f +
            (((size_t)(t & 3) * 4 + m0) * 24 + kg * 12) * 512 + laneo;
        gemm_frag<KCW>(A0, A0 + 12288, W, a00, a01, a10, a11);
      } else {
        const f16_t* A0 = h1f +
            (((size_t)((t + 3) & 3) * 4 + m0) * 24 + (kg - 2) * 12) * 512 + laneo;
        gemm_frag<KCW>(A0, A0 + 12288, W, a00, a01, a10, a11);
      }
    }

    // ---- partial-sum exchange (C layout: col=lane&15, row=l4*4+r) ----
#pragma unroll
    for (int r = 0; r < 4; ++r) {
      pre[kg][m0 * 16 + l4 * 4 + r][l15]           = a00[r];
      pre[kg][m0 * 16 + l4 * 4 + r][16 + l15]      = a01[r];
      pre[kg][m0 * 16 + 16 + l4 * 4 + r][l15]      = a10[r];
      pre[kg][m0 * 16 + 16 + l4 * 4 + r][16 + l15] = a11[r];
    }
    __syncthreads();

    // ---- gate phase: thread = (u = tid&7, b = tid>>3) ----
    float g0 = pre[0][b][4 * u + 0] + pre[1][b][4 * u + 0] + pre[2][b][4 * u + 0] + pre[3][b][4 * u + 0] + bsL[4 * u + 0];
    float g1 = pre[0][b][4 * u + 1] + pre[1][b][4 * u + 1] + pre[2][b][4 * u + 1] + pre[3][b][4 * u + 1] + bsL[4 * u + 1];
    float g2 = pre[0][b][4 * u + 2] + pre[1][b][4 * u + 2] + pre[2][b][4 * u + 2] + pre[3][b][4 * u + 2] + bsL[4 * u + 2];
    float g3 = pre[0][b][4 * u + 3] + pre[1][b][4 * u + 3] + pre[2][b][4 * u + 3] + pre[3][b][4 * u + 3] + bsL[4 * u + 3];
    float ig = sigf(g0), fg = sigf(g1), gg = tanhf(g2), og = sigf(g3);
    c_reg = fg * c_reg + ig * gg;
    float h = og * tanhf(c_reg);
    ring[(size_t)(t & 3) * 49152 + hbase] = (f16_t)h;
    if constexpr (IS_L1) {
      out[((size_t)b * T_ + t) * H_ + j] = h;  // ys
      if (t == T_ - 1) {
        out[BTH + BH + (size_t)b * H_ + j] = h;
        out[BTH + 3 * BH + (size_t)b * H_ + j] = c_reg;
      }
    } else {
      if (t == T_ - 1) {
        out[BTH + (size_t)b * H_ + j] = h;
        out[BTH + 2 * BH + (size_t)b * H_ + j] = c_reg;
      }
    }
    __syncthreads();

    // ---- publish ----
    if (tid == 0) {
      __builtin_amdgcn_fence(__ATOMIC_RELEASE, "agent");
      __hip_atomic_fetch_add((IS_L1 ? cnt1 : cnt0) + t, 1, __ATOMIC_RELAXED,
                             __HIP_MEMORY_SCOPE_AGENT);
    }
  }
}

__launch_bounds__(512, 2)
__global__ void k_lstm(const f16_t* __restrict__ Xf,
                       const f16_t* __restrict__ Wih0f, const f16_t* __restrict__ Whh0f,
                       const f16_t* __restrict__ Wih1f, const f16_t* __restrict__ Whh1f,
                       const float* __restrict__ bsum0, const float* __restrict__ bsum1,
                       f16_t* __restrict__ h0f, f16_t* __restrict__ h1f,
                       int* __restrict__ cnt0, int* __restrict__ cnt1,
                       float* __restrict__ out) {
  __shared__ float pre[4][64][33];
  __shared__ float bsL[32];
  const int wg = blockIdx.x;
  if (wg < 96)
    run_layer<8, false>(wg, Xf, Wih0f, Whh0f, bsum0, h0f, h1f, cnt0, cnt1, out, pre, bsL);
  else
    run_layer<12, true>(wg - 96, Xf, Wih1f, Whh1f, bsum1, h0f, h1f, cnt0, cnt1, out, pre, bsL);
}

// ---------------------------------------------------------------------------
extern "C" void kernel_launch(void* const* d_in, const int* in_sizes, int n_in,
                              void* d_out, int out_size, void* d_ws, size_t ws_size,
                              hipStream_t stream) {
  const float* x    = (const float*)d_in[0];
  const float* wih0 = (const float*)d_in[1];
  const float* whh0 = (const float*)d_in[2];
  const float* bih0 = (const float*)d_in[3];
  const float* bhh0 = (const float*)d_in[4];
  const float* wih1 = (const float*)d_in[5];
  const float* whh1 = (const float*)d_in[6];
  const float* bih1 = (const float*)d_in[7];
  const float* bhh1 = (const float*)d_in[8];
  float* out = (float*)d_out;

  char* base = (char*)d_ws;
  size_t off = 0;
  auto take = [&](size_t bytes) -> char* {
    char* r = base + off;
    off = (off + bytes + 255) & ~(size_t)255;
    return r;
  };
  f16_t* Wih0f = (f16_t*)take((size_t)G4H * I_ * 2);
  f16_t* Whh0f = (f16_t*)take((size_t)G4H * H_ * 2);
  f16_t* Wih1f = (f16_t*)take((size_t)G4H * H_ * 2);
  f16_t* Whh1f = (f16_t*)take((size_t)G4H * H_ * 2);
  f16_t* Xf    = (f16_t*)take((size_t)4 * T_ * 8 * 64 * 8 * 2);
  float* bsum0 = (float*)take((size_t)G4H * 4);
  float* bsum1 = (float*)take((size_t)G4H * 4);
  // state (zeroed each call): h0f + h1f rings (4 slots x 49152 f16 each) + flags
  const size_t ringBytes = (size_t)4 * 49152 * 2;  // per ring, 393216 B
  const size_t cntBytes = (size_t)T_ * 4;          // per counter array
  const size_t stateBytes = 2 * ringBytes + 2 * cntBytes;
  char* st = take(stateBytes);
  f16_t* h0f = (f16_t*)st;
  f16_t* h1f = h0f + 4 * 49152;
  int* cnt0 = (int*)(h1f + 4 * 49152);
  int* cnt1 = cnt0 + T_;

  k_packW<<<768, 256, 0, stream>>>(wih0, Wih0f, I_, 8, G4H * I_);
  k_packW<<<2048, 256, 0, stream>>>(whh0, Whh0f, H_, 24, G4H * H_);
  k_packW<<<2048, 256, 0, stream>>>(wih1, Wih1f, H_, 24, G4H * H_);
  k_packW<<<2048, 256, 0, stream>>>(whh1, Whh1f, H_, 24, G4H * H_);
  k_packX<<<4096, 256, 0, stream>>>(x, Xf);
  k_bias<<<12, 256, 0, stream>>>(bih0, bhh0, bsum0);
  k_bias<<<12, 256, 0, stream>>>(bih1, bhh1, bsum1);
  k_zero<<<(int)((stateBytes / 16 + 255) / 256), 256, 0, stream>>>(
      (int4*)st, (int)(stateBytes / 16));

  k_lstm<<<192, 512, 0, stream>>>(Xf, Wih0f, Whh0f, Wih1f, Whh1f, bsum0, bsum1,
                                  h0f, h1f, cnt0, cnt1, out);
}

// Round 4
// 5346.889 us; speedup vs baseline: 2.1662x; 2.1662x over previous
//
#include <hip/hip_runtime.h>
#include <math.h>

// ---------------------------------------------------------------------------
// 2-layer LSTM, B=64 T=512 I=256 H=768, fp32 in/out.
// Round 4: persistent kernel, weights in LDS (dynamic ~133KB, 1 WG/CU),
// cross-WG h exchange via per-access device-scope relaxed atomics (L3
// coherence point) -- NO cache-wide fences. Flags: vmcnt(0) + relaxed add.
// fp16 MFMA 16x16x32, fragment-major operands (round-2 layout).
// ---------------------------------------------------------------------------

#define B_   64
#define T_   512
#define I_   256
#define H_   768
#define G4H  3072

constexpr size_t BTH = (size_t)B_ * T_ * H_;   // 25165824
constexpr size_t BH  = (size_t)B_ * H_;        // 49152

using f16_t = _Float16;
using f16x8 = __attribute__((ext_vector_type(8))) _Float16;
using f32x4 = __attribute__((ext_vector_type(4))) float;
typedef unsigned long long u64;

#define MFMA(a, b, c) __builtin_amdgcn_mfma_f32_16x16x32_f16((a), (b), (c), 0, 0, 0)

// LDS partition (bytes): WL 0..98304 | pre 98304..132096 | hstage ..133120 | bsL ..133248
#define SMEM_BYTES 133248

// ---------------------------------------------------------------------------
__global__ void k_packW(const float* __restrict__ src, f16_t* __restrict__ dst,
                        int K, int KC, int total) {
  int i = blockIdx.x * blockDim.x + threadIdx.x;
  int stride = gridDim.x * blockDim.x;
  for (; i < total; i += stride) {
    int e = i & 7;
    int lane = (i >> 3) & 63;
    int rest = i >> 9;          // ptile*KC + kc
    int kc = rest % KC;
    int ptile = rest / KC;
    int p = ptile * 16 + (lane & 15);
    int k = kc * 32 + (lane >> 4) * 8 + e;
    int r = (p & 3) * H_ + (p >> 2);
    dst[i] = (f16_t)src[(size_t)r * K + k];
  }
}

__global__ void k_packX(const float* __restrict__ x, f16_t* __restrict__ dst) {
  int i = blockIdx.x * blockDim.x + threadIdx.x;
  int stride = gridDim.x * blockDim.x;
  const int total = 4 * T_ * 8 * 64 * 8;  // 8,388,608
  for (; i < total; i += stride) {
    int e = i & 7;
    int lane = (i >> 3) & 63;
    int kc = (i >> 9) & 7;
    int t = (i >> 12) & 511;
    int mtile = i >> 21;
    int b = mtile * 16 + (lane & 15);
    int k = kc * 32 + (lane >> 4) * 8 + e;
    dst[i] = (f16_t)x[((size_t)b * T_ + t) * I_ + k];
  }
}

__global__ void k_bias(const float* __restrict__ bih, const float* __restrict__ bhh,
                       float* __restrict__ bsum) {
  int p = blockIdx.x * blockDim.x + threadIdx.x;
  if (p < G4H) {
    int r = (p & 3) * H_ + (p >> 2);
    bsum[p] = bih[r] + bhh[r];
  }
}

__global__ void k_zero(int4* __restrict__ d, int n) {
  int i = blockIdx.x * blockDim.x + threadIdx.x;
  if (i < n) d[i] = make_int4(0, 0, 0, 0);
}

__device__ __forceinline__ float sigf(float v) { return 1.0f / (1.0f + expf(-v)); }

__device__ __forceinline__ void wait_ge(const int* p, int target) {
  while (__hip_atomic_load(p, __ATOMIC_RELAXED, __HIP_MEMORY_SCOPE_AGENT) < target)
    __builtin_amdgcn_s_sleep(1);
}

union U16 {
  u64 u[2];
  f16x8 v;
};

// ---------------------------------------------------------------------------
// Persistent per-layer loop. 8 waves = mg(2) x kg(4). Wave: 2x2 tile
// (2 mtiles x 2 ptiles). W slices in LDS. h rings in global, accessed with
// device-scope relaxed atomics. Ring layout: [slot(4)][mtile(4)][kc(24)][512].
template <int KCW, bool IS_L1>
__device__ __forceinline__ void run_layer(
    int ws, const f16_t* __restrict__ Xf, const f16_t* __restrict__ Wihf,
    const f16_t* __restrict__ Whhf, const float* __restrict__ bsum,
    f16_t* __restrict__ h0f, f16_t* __restrict__ h1f, int* __restrict__ cnt0,
    int* __restrict__ cnt1, float* __restrict__ out, char* smem) {
  f16_t* WL = (f16_t*)smem;                              // [4 kg][2 p][KCW][512]
  float (*pre)[64][33] = (float (*)[64][33])(smem + 98304);
  f16_t* hstage = (f16_t*)(smem + 132096);               // [64][8]
  float* bsL = (float*)(smem + 133120);                  // [32]

  const int tid = threadIdx.x;
  const int wave = tid >> 6, lane = tid & 63;
  const int kg = wave & 3, mg = wave >> 2;
  const int laneo = lane * 8;
  const int pt0 = ws * 2, m0 = mg * 2;
  const int l15 = lane & 15, l4 = lane >> 4;

  if (tid < 32) bsL[tid] = bsum[ws * 32 + tid];

  // ---- stage W into LDS (mg==0 waves; mg0/mg1 share the same kg chunk) ----
  if (mg == 0) {
    const f16_t* src;
    int KC, kc0;
    if constexpr (!IS_L1) {
      if (kg == 0) { src = Wihf; KC = 8;  kc0 = 0; }
      else         { src = Whhf; KC = 24; kc0 = (kg - 1) * 8; }
    } else {
      if (kg < 2)  { src = Wihf; KC = 24; kc0 = kg * 12; }
      else         { src = Whhf; KC = 24; kc0 = (kg - 2) * 12; }
    }
#pragma unroll
    for (int p = 0; p < 2; ++p)
#pragma unroll
      for (int i = 0; i < KCW; ++i)
        *(uint4*)(WL + ((size_t)((kg * 2 + p) * KCW + i)) * 512 + laneo) =
            *(const uint4*)(src + ((size_t)(pt0 + p) * KC + kc0 + i) * 512 + laneo);
  }

  float c_reg = 0.f;
  const int u = tid & 7, b = tid >> 3;
  const int j = ws * 8 + u;
  f16_t* ring = IS_L1 ? h1f : h0f;

  __syncthreads();

  for (int t = 0; t < T_; ++t) {
    // ---- flag waits (whole wave held by lane-0 exec-masked spin) ----
    if constexpr (!IS_L1) {
      if (kg != 0 && lane == 0) {
        if (t >= 1) wait_ge(cnt0 + t - 1, 96);   // h0[t-1] ready
        if (t >= 4) wait_ge(cnt1 + t - 4, 96);   // slot t&3 reusable
      }
    } else {
      if (lane == 0) {
        if (kg < 2) wait_ge(cnt0 + t, 96);            // h0[t] ready
        else if (t >= 1) wait_ge(cnt1 + t - 1, 96);   // h1[t-1] ready
      }
    }

    f32x4 a00 = {0.f, 0.f, 0.f, 0.f};
    f32x4 a01 = {0.f, 0.f, 0.f, 0.f};
    f32x4 a10 = {0.f, 0.f, 0.f, 0.f};
    f32x4 a11 = {0.f, 0.f, 0.f, 0.f};

    const f16_t* wl0 = WL + (size_t)(kg * 2) * KCW * 512 + laneo;
    const f16_t* wl1 = wl0 + (size_t)KCW * 512;

    if (!IS_L1 && kg == 0) {
      // x_t @ Wih0^T, plain cached loads (Xf visible via dispatch-boundary flush)
      const f16_t* A0 = Xf + ((size_t)m0 * T_ + t) * 4096 + laneo;
      const f16_t* A1 = A0 + (size_t)T_ * 4096;
#pragma unroll
      for (int i = 0; i < KCW; ++i) {
        f16x8 x0 = *(const f16x8*)(A0 + (size_t)i * 512);
        f16x8 x1 = *(const f16x8*)(A1 + (size_t)i * 512);
        f16x8 w0 = *(const f16x8*)(wl0 + (size_t)i * 512);
        f16x8 w1 = *(const f16x8*)(wl1 + (size_t)i * 512);
        a00 = MFMA(x0, w0, a00);
        a01 = MFMA(x0, w1, a01);
        a10 = MFMA(x1, w0, a10);
        a11 = MFMA(x1, w1, a11);
      }
    } else {
      const f16_t* base;
      if constexpr (!IS_L1) {
        base = h0f + ((size_t)(((t + 3) & 3) * 4 + m0) * 24 + (kg - 1) * 8) * 512 + laneo;
      } else {
        if (kg < 2)
          base = h0f + ((size_t)((t & 3) * 4 + m0) * 24 + kg * 12) * 512 + laneo;
        else
          base = h1f + ((size_t)(((t + 3) & 3) * 4 + m0) * 24 + (kg - 2) * 12) * 512 + laneo;
      }
      U16 A0f[KCW], A1f[KCW];
#pragma unroll
      for (int i = 0; i < KCW; ++i) {
        const u64* p0 = (const u64*)(base + (size_t)i * 512);
        const u64* p1 = (const u64*)(base + 12288 + (size_t)i * 512);
        A0f[i].u[0] = __hip_atomic_load(p0,     __ATOMIC_RELAXED, __HIP_MEMORY_SCOPE_AGENT);
        A0f[i].u[1] = __hip_atomic_load(p0 + 1, __ATOMIC_RELAXED, __HIP_MEMORY_SCOPE_AGENT);
        A1f[i].u[0] = __hip_atomic_load(p1,     __ATOMIC_RELAXED, __HIP_MEMORY_SCOPE_AGENT);
        A1f[i].u[1] = __hip_atomic_load(p1 + 1, __ATOMIC_RELAXED, __HIP_MEMORY_SCOPE_AGENT);
      }
#pragma unroll
      for (int i = 0; i < KCW; ++i) {
        f16x8 w0 = *(const f16x8*)(wl0 + (size_t)i * 512);
        f16x8 w1 = *(const f16x8*)(wl1 + (size_t)i * 512);
        a00 = MFMA(A0f[i].v, w0, a00);
        a01 = MFMA(A0f[i].v, w1, a01);
        a10 = MFMA(A1f[i].v, w0, a10);
        a11 = MFMA(A1f[i].v, w1, a11);
      }
    }

    // ---- partial-sum exchange (C layout: col=lane&15, row=l4*4+r) ----
#pragma unroll
    for (int r = 0; r < 4; ++r) {
      pre[kg][m0 * 16 + l4 * 4 + r][l15]           = a00[r];
      pre[kg][m0 * 16 + l4 * 4 + r][16 + l15]      = a01[r];
      pre[kg][m0 * 16 + 16 + l4 * 4 + r][l15]      = a10[r];
      pre[kg][m0 * 16 + 16 + l4 * 4 + r][16 + l15] = a11[r];
    }
    __syncthreads();

    // ---- gate phase: thread = (u = tid&7, b = tid>>3) ----
    {
      float g0 = pre[0][b][4 * u + 0] + pre[1][b][4 * u + 0] + pre[2][b][4 * u + 0] + pre[3][b][4 * u + 0] + bsL[4 * u + 0];
      float g1 = pre[0][b][4 * u + 1] + pre[1][b][4 * u + 1] + pre[2][b][4 * u + 1] + pre[3][b][4 * u + 1] + bsL[4 * u + 1];
      float g2 = pre[0][b][4 * u + 2] + pre[1][b][4 * u + 2] + pre[2][b][4 * u + 2] + pre[3][b][4 * u + 2] + bsL[4 * u + 2];
      float g3 = pre[0][b][4 * u + 3] + pre[1][b][4 * u + 3] + pre[2][b][4 * u + 3] + pre[3][b][4 * u + 3] + bsL[4 * u + 3];
      float ig = sigf(g0), fg = sigf(g1), gg = tanhf(g2), og = sigf(g3);
      c_reg = fg * c_reg + ig * gg;
      float h = og * tanhf(c_reg);
      hstage[b * 8 + u] = (f16_t)h;
      if constexpr (IS_L1) {
        out[((size_t)b * T_ + t) * H_ + j] = h;  // ys
        if (t == T_ - 1) {
          out[BTH + BH + (size_t)b * H_ + j] = h;
          out[BTH + 3 * BH + (size_t)b * H_ + j] = c_reg;
        }
      } else {
        if (t == T_ - 1) {
          out[BTH + (size_t)b * H_ + j] = h;
          out[BTH + 2 * BH + (size_t)b * H_ + j] = c_reg;
        }
      }
    }
    __syncthreads();

    // ---- wave 0: flush hstage -> ring (device-scope), then publish ----
    if (tid < 64) {
      const int bb = tid;
      uint4 hv = *(uint4*)(hstage + bb * 8);
      size_t rbase = (size_t)(t & 3) * 49152 +
                     ((size_t)(bb >> 4) * 24 + (ws >> 2)) * 512 +
                     (size_t)((ws & 3) * 16 + (bb & 15)) * 8;
      u64* dst = (u64*)(ring + rbase);
      u64 lo = ((u64)hv.y << 32) | hv.x;
      u64 hi = ((u64)hv.w << 32) | hv.z;
      __hip_atomic_store(dst,     lo, __ATOMIC_RELAXED, __HIP_MEMORY_SCOPE_AGENT);
      __hip_atomic_store(dst + 1, hi, __ATOMIC_RELAXED, __HIP_MEMORY_SCOPE_AGENT);
      asm volatile("s_waitcnt vmcnt(0)" ::: "memory");
      if (tid == 0)
        __hip_atomic_fetch_add((IS_L1 ? cnt1 : cnt0) + t, 1, __ATOMIC_RELAXED,
                               __HIP_MEMORY_SCOPE_AGENT);
    }
  }
}

__launch_bounds__(512, 2)
__global__ void k_lstm(const f16_t* __restrict__ Xf,
                       const f16_t* __restrict__ Wih0f, const f16_t* __restrict__ Whh0f,
                       const f16_t* __restrict__ Wih1f, const f16_t* __restrict__ Whh1f,
                       const float* __restrict__ bsum0, const float* __restrict__ bsum1,
                       f16_t* __restrict__ h0f, f16_t* __restrict__ h1f,
                       int* __restrict__ cnt0, int* __restrict__ cnt1,
                       float* __restrict__ out) {
  extern __shared__ char smem[];
  const int wg = blockIdx.x;
  if (wg < 96)
    run_layer<8, false>(wg, Xf, Wih0f, Whh0f, bsum0, h0f, h1f, cnt0, cnt1, out, smem);
  else
    run_layer<12, true>(wg - 96, Xf, Wih1f, Whh1f, bsum1, h0f, h1f, cnt0, cnt1, out, smem);
}

// ---------------------------------------------------------------------------
extern "C" void kernel_launch(void* const* d_in, const int* in_sizes, int n_in,
                              void* d_out, int out_size, void* d_ws, size_t ws_size,
                              hipStream_t stream) {
  const float* x    = (const float*)d_in[0];
  const float* wih0 = (const float*)d_in[1];
  const float* whh0 = (const float*)d_in[2];
  const float* bih0 = (const float*)d_in[3];
  const float* bhh0 = (const float*)d_in[4];
  const float* wih1 = (const float*)d_in[5];
  const float* whh1 = (const float*)d_in[6];
  const float* bih1 = (const float*)d_in[7];
  const float* bhh1 = (const float*)d_in[8];
  float* out = (float*)d_out;

  char* base = (char*)d_ws;
  size_t off = 0;
  auto take = [&](size_t bytes) -> char* {
    char* r = base + off;
    off = (off + bytes + 255) & ~(size_t)255;
    return r;
  };
  f16_t* Wih0f = (f16_t*)take((size_t)G4H * I_ * 2);
  f16_t* Whh0f = (f16_t*)take((size_t)G4H * H_ * 2);
  f16_t* Wih1f = (f16_t*)take((size_t)G4H * H_ * 2);
  f16_t* Whh1f = (f16_t*)take((size_t)G4H * H_ * 2);
  f16_t* Xf    = (f16_t*)take((size_t)4 * T_ * 8 * 64 * 8 * 2);
  float* bsum0 = (float*)take((size_t)G4H * 4);
  float* bsum1 = (float*)take((size_t)G4H * 4);
  // state (zeroed each call): 2 rings (4 slots x 49152 f16) + 2 flag arrays
  const size_t ringBytes = (size_t)4 * 49152 * 2;  // 393216 each
  const size_t stateBytes = 2 * ringBytes + 2 * (size_t)T_ * 4;
  char* st = take(stateBytes);
  f16_t* h0f = (f16_t*)st;
  f16_t* h1f = h0f + 4 * 49152;
  int* cnt0 = (int*)(h1f + 4 * 49152);
  int* cnt1 = cnt0 + T_;

  static bool attr_done = false;
  // idempotent, host-side only (not a stream op) -> graph-capture safe
  hipFuncSetAttribute(reinterpret_cast<const void*>(k_lstm),
                      hipFuncAttributeMaxDynamicSharedMemorySize, SMEM_BYTES);
  (void)attr_done;

  k_packW<<<768, 256, 0, stream>>>(wih0, Wih0f, I_, 8, G4H * I_);
  k_packW<<<2048, 256, 0, stream>>>(whh0, Whh0f, H_, 24, G4H * H_);
  k_packW<<<2048, 256, 0, stream>>>(wih1, Wih1f, H_, 24, G4H * H_);
  k_packW<<<2048, 256, 0, stream>>>(whh1, Whh1f, H_, 24, G4H * H_);
  k_packX<<<4096, 256, 0, stream>>>(x, Xf);
  k_bias<<<12, 256, 0, stream>>>(bih0, bhh0, bsum0);
  k_bias<<<12, 256, 0, stream>>>(bih1, bhh1, bsum1);
  k_zero<<<(int)((stateBytes / 16 + 255) / 256), 256, 0, stream>>>(
      (int4*)st, (int)(stateBytes / 16));

  k_lstm<<<192, 512, SMEM_BYTES, stream>>>(Xf, Wih0f, Whh0f, Wih1f, Whh1f,
                                           bsum0, bsum1, h0f, h1f, cnt0, cnt1, out);
}

// Round 5
// 2826.412 us; speedup vs baseline: 4.0980x; 1.8918x over previous
//
#include <hip/hip_runtime.h>
#include <math.h>

// ---------------------------------------------------------------------------
// 2-layer LSTM, B=64 T=512 I=256 H=768, fp32 in/out.
// Round 5: persistent kernel (192 WGs, weights in LDS). Sync rebuilt:
// per-producer 16B-strided flags (relaxed stores, NO fetch_add), consumer
// waves poll lane-parallel over exactly the producer subset they read.
// Ring depth 8; single off-critical-path L0-vs-L1 safety wait bounds
// run-ahead. fp16 MFMA 16x16x32, fragment-major operands.
// ---------------------------------------------------------------------------

#define B_   64
#define T_   512
#define I_   256
#define H_   768
#define G4H  3072

constexpr size_t BTH = (size_t)B_ * T_ * H_;   // 25165824
constexpr size_t BH  = (size_t)B_ * H_;        // 49152

using f16_t = _Float16;
using f16x8 = __attribute__((ext_vector_type(8))) _Float16;
using f32x4 = __attribute__((ext_vector_type(4))) float;
typedef unsigned long long u64;

#define MFMA(a, b, c) __builtin_amdgcn_mfma_f32_16x16x32_f16((a), (b), (c), 0, 0, 0)

// LDS partition (bytes): WL 0..98304 | pre 98304..132096 | hstage ..133120 | bsL ..133248
#define SMEM_BYTES 133248

// ---------------------------------------------------------------------------
__global__ void k_packW(const float* __restrict__ src, f16_t* __restrict__ dst,
                        int K, int KC, int total) {
  int i = blockIdx.x * blockDim.x + threadIdx.x;
  int stride = gridDim.x * blockDim.x;
  for (; i < total; i += stride) {
    int e = i & 7;
    int lane = (i >> 3) & 63;
    int rest = i >> 9;          // ptile*KC + kc
    int kc = rest % KC;
    int ptile = rest / KC;
    int p = ptile * 16 + (lane & 15);
    int k = kc * 32 + (lane >> 4) * 8 + e;
    int r = (p & 3) * H_ + (p >> 2);
    dst[i] = (f16_t)src[(size_t)r * K + k];
  }
}

__global__ void k_packX(const float* __restrict__ x, f16_t* __restrict__ dst) {
  int i = blockIdx.x * blockDim.x + threadIdx.x;
  int stride = gridDim.x * blockDim.x;
  const int total = 4 * T_ * 8 * 64 * 8;  // 8,388,608
  for (; i < total; i += stride) {
    int e = i & 7;
    int lane = (i >> 3) & 63;
    int kc = (i >> 9) & 7;
    int t = (i >> 12) & 511;
    int mtile = i >> 21;
    int b = mtile * 16 + (lane & 15);
    int k = kc * 32 + (lane >> 4) * 8 + e;
    dst[i] = (f16_t)x[((size_t)b * T_ + t) * I_ + k];
  }
}

__global__ void k_bias(const float* __restrict__ bih, const float* __restrict__ bhh,
                       float* __restrict__ bsum) {
  int p = blockIdx.x * blockDim.x + threadIdx.x;
  if (p < G4H) {
    int r = (p & 3) * H_ + (p >> 2);
    bsum[p] = bih[r] + bhh[r];
  }
}

__global__ void k_zero(int4* __restrict__ d, int n) {
  int i = blockIdx.x * blockDim.x + threadIdx.x;
  if (i < n) d[i] = make_int4(0, 0, 0, 0);
}

// Fast saturating activations: v_exp_f32 (=2^x) + v_rcp_f32. exp2(+-inf)
// saturates -> sig in [0,1], tanh in [-1,1]; accuracy ~1e-6.
__device__ __forceinline__ float sigf(float v) {
  return __builtin_amdgcn_rcpf(1.0f + __builtin_amdgcn_exp2f(v * -1.44269504f));
}
__device__ __forceinline__ float tanhf_fast(float v) {
  return 2.0f * __builtin_amdgcn_rcpf(1.0f + __builtin_amdgcn_exp2f(v * -2.88539008f)) - 1.0f;
}

__device__ __forceinline__ int ld_flag(const int* p) {
  return __hip_atomic_load(p, __ATOMIC_RELAXED, __HIP_MEMORY_SCOPE_AGENT);
}

// Lanes 0..N-1 poll f[lane*4] (16B stride); whole wave exits when all set.
template <int N>
__device__ __forceinline__ void wait_subset(const int* f) {
  static_assert(N <= 64, "subset too large");
  const int lane = threadIdx.x & 63;
  const int* p = f + lane * 4;
  for (;;) {
    int v = (lane < N) ? ld_flag(p) : 1;
    if (__all(v != 0)) return;
    __builtin_amdgcn_s_sleep(1);
  }
}

// Full-96 poll (64 lanes + 32 lanes second load).
__device__ __forceinline__ void wait96(const int* f) {
  const int lane = threadIdx.x & 63;
  for (;;) {
    int v0 = ld_flag(f + lane * 4);
    int v1 = (lane < 32) ? ld_flag(f + (64 + lane) * 4) : 1;
    if (__all(v0 != 0 && v1 != 0)) return;
    __builtin_amdgcn_s_sleep(1);
  }
}

union U16 {
  u64 u[2];
  f16x8 v;
};

// ---------------------------------------------------------------------------
// Persistent per-layer loop. 8 waves = mg(2) x kg(4). Wave: 2x2 tile
// (2 mtiles x 2 ptiles). W slices in LDS. h rings (depth 8) in global via
// device-scope relaxed atomics. Ring layout: [slot(8)][mtile(4)][kc(24)][512].
// Flags: flag[t*128 + ws]*4 ints (16B stride), one per producer WG per step.
template <int KCW, bool IS_L1>
__device__ __forceinline__ void run_layer(
    int ws, const f16_t* __restrict__ Xf, const f16_t* __restrict__ Wihf,
    const f16_t* __restrict__ Whhf, const float* __restrict__ bsum,
    f16_t* __restrict__ h0f, f16_t* __restrict__ h1f, int* __restrict__ flag0,
    int* __restrict__ flag1, float* __restrict__ out, char* smem) {
  f16_t* WL = (f16_t*)smem;                              // [4 kg][2 p][KCW][512]
  float (*pre)[64][33] = (float (*)[64][33])(smem + 98304);
  f16_t* hstage = (f16_t*)(smem + 132096);               // [64][8]
  float* bsL = (float*)(smem + 133120);                  // [32]

  const int tid = threadIdx.x;
  const int wave = tid >> 6, lane = tid & 63;
  const int kg = wave & 3, mg = wave >> 2;
  const int laneo = lane * 8;
  const int pt0 = ws * 2, m0 = mg * 2;
  const int l15 = lane & 15, l4 = lane >> 4;

  if (tid < 32) bsL[tid] = bsum[ws * 32 + tid];

  // ---- stage W into LDS (mg==0 waves) ----
  if (mg == 0) {
    const f16_t* src;
    int KC, kc0;
    if constexpr (!IS_L1) {
      if (kg == 0) { src = Wihf; KC = 8;  kc0 = 0; }
      else         { src = Whhf; KC = 24; kc0 = (kg - 1) * 8; }
    } else {
      if (kg < 2)  { src = Wihf; KC = 24; kc0 = kg * 12; }
      else         { src = Whhf; KC = 24; kc0 = (kg - 2) * 12; }
    }
#pragma unroll
    for (int p = 0; p < 2; ++p)
#pragma unroll
      for (int i = 0; i < KCW; ++i)
        *(uint4*)(WL + ((size_t)((kg * 2 + p) * KCW + i)) * 512 + laneo) =
            *(const uint4*)(src + ((size_t)(pt0 + p) * KC + kc0 + i) * 512 + laneo);
  }

  float c_reg = 0.f;
  const int u = tid & 7, b = tid >> 3;
  const int j = ws * 8 + u;
  f16_t* ring = IS_L1 ? h1f : h0f;
  int* myflag = IS_L1 ? flag1 : flag0;

  __syncthreads();

  for (int t = 0; t < T_; ++t) {
    // ---- input waits: lane-parallel poll over exactly the producers read ----
    if constexpr (!IS_L1) {
      if (kg >= 1) {
        if (t >= 1)
          wait_subset<32>(flag0 + ((size_t)(t - 1) * 128 + (kg - 1) * 32) * 4);
      } else if (mg == 1) {
        // ring-safety: L0 may run at most 8 steps ahead of L1 (h0 slot reuse).
        if (t >= 8) wait96(flag1 + (size_t)(t - 8) * 512);
      }
    } else {
      if (kg < 2) {
        wait_subset<48>(flag0 + ((size_t)t * 128 + kg * 48) * 4);
      } else if (t >= 1) {
        wait_subset<48>(flag1 + ((size_t)(t - 1) * 128 + (kg - 2) * 48) * 4);
      }
    }

    f32x4 a00 = {0.f, 0.f, 0.f, 0.f};
    f32x4 a01 = {0.f, 0.f, 0.f, 0.f};
    f32x4 a10 = {0.f, 0.f, 0.f, 0.f};
    f32x4 a11 = {0.f, 0.f, 0.f, 0.f};

    const f16_t* wl0 = WL + (size_t)(kg * 2) * KCW * 512 + laneo;
    const f16_t* wl1 = wl0 + (size_t)KCW * 512;

    if (!IS_L1 && kg == 0) {
      // x_t @ Wih0^T (no recurrence dependency; overlaps others' waits)
      const f16_t* A0 = Xf + ((size_t)m0 * T_ + t) * 4096 + laneo;
      const f16_t* A1 = A0 + (size_t)T_ * 4096;
#pragma unroll
      for (int i = 0; i < KCW; ++i) {
        f16x8 x0 = *(const f16x8*)(A0 + (size_t)i * 512);
        f16x8 x1 = *(const f16x8*)(A1 + (size_t)i * 512);
        f16x8 w0 = *(const f16x8*)(wl0 + (size_t)i * 512);
        f16x8 w1 = *(const f16x8*)(wl1 + (size_t)i * 512);
        a00 = MFMA(x0, w0, a00);
        a01 = MFMA(x0, w1, a01);
        a10 = MFMA(x1, w0, a10);
        a11 = MFMA(x1, w1, a11);
      }
    } else {
      const f16_t* base;
      if constexpr (!IS_L1) {
        base = h0f + ((size_t)(((t + 7) & 7) * 4 + m0) * 24 + (kg - 1) * 8) * 512 + laneo;
      } else {
        if (kg < 2)
          base = h0f + ((size_t)((t & 7) * 4 + m0) * 24 + kg * 12) * 512 + laneo;
        else
          base = h1f + ((size_t)(((t + 7) & 7) * 4 + m0) * 24 + (kg - 2) * 12) * 512 + laneo;
      }
      U16 A0f[KCW], A1f[KCW];
#pragma unroll
      for (int i = 0; i < KCW; ++i) {
        const u64* p0 = (const u64*)(base + (size_t)i * 512);
        const u64* p1 = (const u64*)(base + 12288 + (size_t)i * 512);
        A0f[i].u[0] = __hip_atomic_load(p0,     __ATOMIC_RELAXED, __HIP_MEMORY_SCOPE_AGENT);
        A0f[i].u[1] = __hip_atomic_load(p0 + 1, __ATOMIC_RELAXED, __HIP_MEMORY_SCOPE_AGENT);
        A1f[i].u[0] = __hip_atomic_load(p1,     __ATOMIC_RELAXED, __HIP_MEMORY_SCOPE_AGENT);
        A1f[i].u[1] = __hip_atomic_load(p1 + 1, __ATOMIC_RELAXED, __HIP_MEMORY_SCOPE_AGENT);
      }
#pragma unroll
      for (int i = 0; i < KCW; ++i) {
        f16x8 w0 = *(const f16x8*)(wl0 + (size_t)i * 512);
        f16x8 w1 = *(const f16x8*)(wl1 + (size_t)i * 512);
        a00 = MFMA(A0f[i].v, w0, a00);
        a01 = MFMA(A0f[i].v, w1, a01);
        a10 = MFMA(A1f[i].v, w0, a10);
        a11 = MFMA(A1f[i].v, w1, a11);
      }
    }

    // ---- partial-sum exchange (C layout: col=lane&15, row=l4*4+r) ----
#pragma unroll
    for (int r = 0; r < 4; ++r) {
      pre[kg][m0 * 16 + l4 * 4 + r][l15]           = a00[r];
      pre[kg][m0 * 16 + l4 * 4 + r][16 + l15]      = a01[r];
      pre[kg][m0 * 16 + 16 + l4 * 4 + r][l15]      = a10[r];
      pre[kg][m0 * 16 + 16 + l4 * 4 + r][16 + l15] = a11[r];
    }
    __syncthreads();

    // ---- gate phase: thread = (u = tid&7, b = tid>>3) ----
    {
      float g0 = pre[0][b][4 * u + 0] + pre[1][b][4 * u + 0] + pre[2][b][4 * u + 0] + pre[3][b][4 * u + 0] + bsL[4 * u + 0];
      float g1 = pre[0][b][4 * u + 1] + pre[1][b][4 * u + 1] + pre[2][b][4 * u + 1] + pre[3][b][4 * u + 1] + bsL[4 * u + 1];
      float g2 = pre[0][b][4 * u + 2] + pre[1][b][4 * u + 2] + pre[2][b][4 * u + 2] + pre[3][b][4 * u + 2] + bsL[4 * u + 2];
      float g3 = pre[0][b][4 * u + 3] + pre[1][b][4 * u + 3] + pre[2][b][4 * u + 3] + pre[3][b][4 * u + 3] + bsL[4 * u + 3];
      float ig = sigf(g0), fg = sigf(g1), gg = tanhf_fast(g2), og = sigf(g3);
      c_reg = fg * c_reg + ig * gg;
      float h = og * tanhf_fast(c_reg);
      hstage[b * 8 + u] = (f16_t)h;
      if constexpr (IS_L1) {
        out[((size_t)b * T_ + t) * H_ + j] = h;  // ys
        if (t == T_ - 1) {
          out[BTH + BH + (size_t)b * H_ + j] = h;
          out[BTH + 3 * BH + (size_t)b * H_ + j] = c_reg;
        }
      } else {
        if (t == T_ - 1) {
          out[BTH + (size_t)b * H_ + j] = h;
          out[BTH + 2 * BH + (size_t)b * H_ + j] = c_reg;
        }
      }
    }
    __syncthreads();

    // ---- wave 0: flush hstage -> ring (device-scope), then post flag ----
    if (tid < 64) {
      const int bb = tid;
      uint4 hv = *(uint4*)(hstage + bb * 8);
      size_t rbase = (size_t)(t & 7) * 49152 +
                     ((size_t)(bb >> 4) * 24 + (ws >> 2)) * 512 +
                     (size_t)((ws & 3) * 16 + (bb & 15)) * 8;
      u64* dst = (u64*)(ring + rbase);
      u64 lo = ((u64)hv.y << 32) | hv.x;
      u64 hi = ((u64)hv.w << 32) | hv.z;
      __hip_atomic_store(dst,     lo, __ATOMIC_RELAXED, __HIP_MEMORY_SCOPE_AGENT);
      __hip_atomic_store(dst + 1, hi, __ATOMIC_RELAXED, __HIP_MEMORY_SCOPE_AGENT);
      asm volatile("s_waitcnt vmcnt(0)" ::: "memory");
      if (tid == 0)
        __hip_atomic_store(myflag + ((size_t)t * 128 + ws) * 4, 1,
                           __ATOMIC_RELAXED, __HIP_MEMORY_SCOPE_AGENT);
    }
  }
}

__launch_bounds__(512, 2)
__global__ void k_lstm(const f16_t* __restrict__ Xf,
                       const f16_t* __restrict__ Wih0f, const f16_t* __restrict__ Whh0f,
                       const f16_t* __restrict__ Wih1f, const f16_t* __restrict__ Whh1f,
                       const float* __restrict__ bsum0, const float* __restrict__ bsum1,
                       f16_t* __restrict__ h0f, f16_t* __restrict__ h1f,
                       int* __restrict__ flag0, int* __restrict__ flag1,
                       float* __restrict__ out) {
  extern __shared__ char smem[];
  const int wg = blockIdx.x;
  if (wg < 96)
    run_layer<8, false>(wg, Xf, Wih0f, Whh0f, bsum0, h0f, h1f, flag0, flag1, out, smem);
  else
    run_layer<12, true>(wg - 96, Xf, Wih1f, Whh1f, bsum1, h0f, h1f, flag0, flag1, out, smem);
}

// ---------------------------------------------------------------------------
extern "C" void kernel_launch(void* const* d_in, const int* in_sizes, int n_in,
                              void* d_out, int out_size, void* d_ws, size_t ws_size,
                              hipStream_t stream) {
  const float* x    = (const float*)d_in[0];
  const float* wih0 = (const float*)d_in[1];
  const float* whh0 = (const float*)d_in[2];
  const float* bih0 = (const float*)d_in[3];
  const float* bhh0 = (const float*)d_in[4];
  const float* wih1 = (const float*)d_in[5];
  const float* whh1 = (const float*)d_in[6];
  const float* bih1 = (const float*)d_in[7];
  const float* bhh1 = (const float*)d_in[8];
  float* out = (float*)d_out;

  char* base = (char*)d_ws;
  size_t off = 0;
  auto take = [&](size_t bytes) -> char* {
    char* r = base + off;
    off = (off + bytes + 255) & ~(size_t)255;
    return r;
  };
  f16_t* Wih0f = (f16_t*)take((size_t)G4H * I_ * 2);
  f16_t* Whh0f = (f16_t*)take((size_t)G4H * H_ * 2);
  f16_t* Wih1f = (f16_t*)take((size_t)G4H * H_ * 2);
  f16_t* Whh1f = (f16_t*)take((size_t)G4H * H_ * 2);
  f16_t* Xf    = (f16_t*)take((size_t)4 * T_ * 8 * 64 * 8 * 2);
  float* bsum0 = (float*)take((size_t)G4H * 4);
  float* bsum1 = (float*)take((size_t)G4H * 4);
  // state (zeroed each call): 2 rings (8 slots x 49152 f16) + 2 flag arrays
  // flags: [T][128] x 16B stride = 1 MB each.
  const size_t ringBytes = (size_t)8 * 49152 * 2;        // 786432 each
  const size_t flagBytes = (size_t)T_ * 128 * 4 * 4;     // 1048576 each
  const size_t stateBytes = 2 * ringBytes + 2 * flagBytes;
  char* st = take(stateBytes);
  f16_t* h0f = (f16_t*)st;
  f16_t* h1f = h0f + 8 * 49152;
  int* flag0 = (int*)(h1f + 8 * 49152);
  int* flag1 = flag0 + (size_t)T_ * 128 * 4;

  hipFuncSetAttribute(reinterpret_cast<const void*>(k_lstm),
                      hipFuncAttributeMaxDynamicSharedMemorySize, SMEM_BYTES);

  k_packW<<<768, 256, 0, stream>>>(wih0, Wih0f, I_, 8, G4H * I_);
  k_packW<<<2048, 256, 0, stream>>>(whh0, Whh0f, H_, 24, G4H * H_);
  k_packW<<<2048, 256, 0, stream>>>(wih1, Wih1f, H_, 24, G4H * H_);
  k_packW<<<2048, 256, 0, stream>>>(whh1, Whh1f, H_, 24, G4H * H_);
  k_packX<<<4096, 256, 0, stream>>>(x, Xf);
  k_bias<<<12, 256, 0, stream>>>(bih0, bhh0, bsum0);
  k_bias<<<12, 256, 0, stream>>>(bih1, bhh1, bsum1);
  k_zero<<<(int)((stateBytes / 16 + 255) / 256), 256, 0, stream>>>(
      (int4*)st, (int)(stateBytes / 16));

  k_lstm<<<192, 512, SMEM_BYTES, stream>>>(Xf, Wih0f, Whh0f, Wih1f, Whh1f,
                                           bsum0, bsum1, h0f, h1f, flag0, flag1, out);
}